// Round 1
// baseline (37.484 us; speedup 1.0000x reference)
//
#include <hip/hip_runtime.h>

// Problem constants (b=4, n=64, d=64, E=4096)
// z_t layout in ws: [b][d][i][k] -> ((b*64+d)*64+i)*64+k   (4 MB)
// a1[r][e], a3[r][e] : r = b*64+i (node row), 64 KB each

__global__ __launch_bounds__(256) void k_pathlin(
    const float* __restrict__ pe, const float* __restrict__ Whz,
    const float* __restrict__ bhz, float* __restrict__ zt) {
  int bi = blockIdx.x;            // b*64 + i
  int b  = bi >> 6, i = bi & 63;
  int t = threadIdx.x, lane = t & 63, g = t >> 6;
  __shared__ float pel[64][64];   // pe[k][c]
  __shared__ float Wl[64][64];    // W[c][d]
  __shared__ float zl[64][65];    // z[k][d], padded for transpose read
  const float* peb = pe + (size_t)bi * 4096;
  for (int r = g; r < 64; r += 4) {
    pel[r][lane] = peb[r * 64 + lane];
    Wl[r][lane]  = Whz[r * 64 + lane];
  }
  __syncthreads();
  // compute: lane = d, wave g owns k in [g*16, g*16+16)
  float acc[16];
  float bv = bhz[lane];
#pragma unroll
  for (int kk = 0; kk < 16; ++kk) acc[kk] = bv;
  int k0 = g * 16;
  for (int c = 0; c < 64; c += 4) {
    float w0 = Wl[c + 0][lane], w1 = Wl[c + 1][lane];
    float w2 = Wl[c + 2][lane], w3 = Wl[c + 3][lane];
#pragma unroll
    for (int kk = 0; kk < 16; ++kk) {
      const float4 p = *(const float4*)&pel[k0 + kk][c];   // wave-uniform b128
      acc[kk] += p.x * w0 + p.y * w1 + p.z * w2 + p.w * w3;
    }
  }
#pragma unroll
  for (int kk = 0; kk < 16; ++kk) zl[k0 + kk][lane] = acc[kk];
  __syncthreads();
  // write transposed: lane = k, wave g owns d in [g*16, g*16+16)
  float* ztb = zt + (size_t)b * 262144 + (size_t)i * 64;   // + d*4096 + k
#pragma unroll
  for (int dd = 0; dd < 16; ++dd) {
    int d2 = g * 16 + dd;
    ztb[(size_t)d2 * 4096 + lane] = zl[lane][d2];
  }
}

__global__ __launch_bounds__(256) void k_tropical(float* __restrict__ zt) {
  int blk = blockIdx.x;           // b*64 + d
  float* Ag = zt + (size_t)blk * 4096;
  __shared__ float A[64][64];
  int t = threadIdx.x, lane = t & 63, g = t >> 6;
  {
    const float4* s4 = (const float4*)Ag;
    float4* d4 = (float4*)&A[0][0];
    for (int idx = t; idx < 1024; idx += 256) d4[idx] = s4[idx];
  }
  __syncthreads();
  int j = lane, i0 = g * 16;
  float acc[16];
#pragma unroll
  for (int ii = 0; ii < 16; ++ii) acc[ii] = A[i0 + ii][j];  // z term of max(z_conv,z)
  for (int k = 0; k < 64; k += 4) {
    float b0 = A[k + 0][j], b1 = A[k + 1][j];
    float b2 = A[k + 2][j], b3 = A[k + 3][j];
#pragma unroll
    for (int ii = 0; ii < 16; ++ii) {
      const float4 a = *(const float4*)&A[i0 + ii][k];      // wave-uniform b128
      float m0 = fmaxf(a.x + b0, a.y + b1);
      float m1 = fmaxf(a.z + b2, a.w + b3);
      acc[ii] = fmaxf(acc[ii], fmaxf(m0, m1));
    }
  }
  // in-place overwrite of this block's exclusive 16KB slice (reads were LDS-only)
#pragma unroll
  for (int ii = 0; ii < 16; ++ii) Ag[(i0 + ii) * 64 + j] = acc[ii];
}

__global__ __launch_bounds__(256) void k_nodeproj(
    const float* __restrict__ ne, const float* __restrict__ Wzz,
    float* __restrict__ a1, float* __restrict__ a3) {
  int t = threadIdx.x, lane = t & 63, g = t >> 6;
  int r = blockIdx.x * 4 + g;
  const float* nr = ne + r * 64;
  float s1 = 0.f, s3 = 0.f;
  for (int d2 = 0; d2 < 64; ++d2) {
    float nv = nr[d2];                       // wave-uniform (scalar load)
    s1 += nv * Wzz[d2 * 64 + lane];          // rows 0..63   (n_i part)
    s3 += nv * Wzz[(128 + d2) * 64 + lane];  // rows 128..191 (n_j part)
  }
  a1[r * 64 + lane] = s1;
  a3[r * 64 + lane] = s3;
}

__global__ __launch_bounds__(256) void k_upath(
    const float* __restrict__ zt, const float* __restrict__ Wzz,
    const float* __restrict__ bzz, const float* __restrict__ a1,
    const float* __restrict__ a3, const float* __restrict__ pe,
    float* __restrict__ out1) {
  int bi = blockIdx.x;            // b*64 + i
  int b  = bi >> 6;
  int t = threadIdx.x, lane = t & 63, g = t >> 6;
  __shared__ float zf[64][64];    // [d][j]
  __shared__ float W2[64][64];    // [d][e] = W_zz rows 64..127
  const float* ztb = zt + (size_t)b * 262144 + (size_t)(bi & 63) * 64;
  for (int d2 = g; d2 < 64; d2 += 4) {
    zf[d2][lane] = ztb[(size_t)d2 * 4096 + lane];
    W2[d2][lane] = Wzz[(64 + d2) * 64 + lane];
  }
  __syncthreads();
  int e = lane, j0 = g * 16;
  float base = a1[bi * 64 + e] + bzz[e];
  float acc[16];
#pragma unroll
  for (int jj = 0; jj < 16; ++jj) acc[jj] = base;
  for (int d2 = 0; d2 < 64; ++d2) {
    float w = W2[d2][e];
#pragma unroll
    for (int jj = 0; jj < 16; jj += 4) {
      const float4 z4 = *(const float4*)&zf[d2][j0 + jj];   // wave-uniform b128
      acc[jj + 0] += z4.x * w;
      acc[jj + 1] += z4.y * w;
      acc[jj + 2] += z4.z * w;
      acc[jj + 3] += z4.w * w;
    }
  }
  const float* a3b = a3 + (size_t)(b * 64) * 64;
  size_t obase = (size_t)bi * 4096;
#pragma unroll
  for (int jj = 0; jj < 16; ++jj) {
    int j = j0 + jj;
    float v = acc[jj] + a3b[j * 64 + e];
    v = fmaxf(v, 0.f);
    out1[obase + j * 64 + e] = v + pe[obase + j * 64 + e];
  }
}

__global__ __launch_bounds__(256) void k_node(
    const float* __restrict__ ne, const int* __restrict__ eidx,
    const float* __restrict__ Wnm, const float* __restrict__ bnm,
    float* __restrict__ out0) {
  int r = blockIdx.x;
  int t = threadIdx.x, lane = t & 63, g = t >> 6;
  __shared__ int elist[4096];     // wave-segmented: wave g owns [g*1024, g*1024+1024)
  __shared__ int wcnt_s[4];
  __shared__ float part[4][64];
  __shared__ float nl[64], al[64];
  const int* srcv = eidx;
  const int* dstv = eidx + 4096;
  // phase 1: deterministic ballot compaction. wave g scans edges [g*1024, (g+1)*1024)
  int cntw = 0;
  unsigned long long ltmask = (lane == 63) ? 0x7fffffffffffffffull
                                           : ((1ull << lane) - 1ull);
  for (int q = 0; q < 16; ++q) {
    int e2 = g * 1024 + q * 64 + lane;
    bool match = (dstv[e2] == r);
    unsigned long long mask = __ballot(match);
    if (match) {
      int pos = cntw + __popcll(mask & ltmask);
      elist[g * 1024 + pos] = srcv[e2];
    }
    cntw += __popcll(mask);
  }
  if (lane == 0) wcnt_s[g] = cntw;
  if (t == 0) { }
  __syncthreads();
  // phase 2: wave g sums its own segment in fixed order
  float accA = 0.f;
  int c = wcnt_s[g];
  for (int m = 0; m < c; ++m) accA += ne[elist[g * 1024 + m] * 64 + lane];
  part[g][lane] = accA;
  if (g == 0) nl[lane] = ne[r * 64 + lane];
  __syncthreads();
  if (g == 0)
    al[lane] = part[0][lane] + part[1][lane] + part[2][lane] + part[3][lane];
  __syncthreads();
  // phase 3: u_node row. wave g handles d in [g*16, g*16+16)
  float s = 0.f;
  for (int d2 = g * 16; d2 < g * 16 + 16; ++d2) {
    s += nl[d2] * Wnm[d2 * 64 + lane] + al[d2] * Wnm[(64 + d2) * 64 + lane];
  }
  part[g][lane] = s;
  __syncthreads();
  if (g == 0) {
    float v = part[0][lane] + part[1][lane] + part[2][lane] + part[3][lane]
              + bnm[lane];
    v = fmaxf(v, 0.f);
    out0[r * 64 + lane] = v + nl[lane];
  }
}

extern "C" void kernel_launch(void* const* d_in, const int* in_sizes, int n_in,
                              void* d_out, int out_size, void* d_ws, size_t ws_size,
                              hipStream_t stream) {
  const float* node = (const float*)d_in[0];
  const float* pe   = (const float*)d_in[1];
  const int*   eidx = (const int*)d_in[2];
  const float* Whz  = (const float*)d_in[3];
  const float* bhz  = (const float*)d_in[4];
  const float* Wzz  = (const float*)d_in[5];
  const float* bzz  = (const float*)d_in[6];
  const float* Wnm  = (const float*)d_in[7];
  const float* bnm  = (const float*)d_in[8];
  float* out0 = (float*)d_out;
  float* out1 = out0 + 16384;
  float* zt = (float*)d_ws;                 // 4 MB
  float* a1 = zt + 4 * 64 * 64 * 64;        // 64 KB
  float* a3 = a1 + 256 * 64;                // 64 KB

  hipLaunchKernelGGL(k_pathlin,  dim3(256), dim3(256), 0, stream, pe, Whz, bhz, zt);
  hipLaunchKernelGGL(k_nodeproj, dim3(64),  dim3(256), 0, stream, node, Wzz, a1, a3);
  hipLaunchKernelGGL(k_tropical, dim3(256), dim3(256), 0, stream, zt);
  hipLaunchKernelGGL(k_upath,    dim3(256), dim3(256), 0, stream, zt, Wzz, bzz, a1, a3, pe, out1);
  hipLaunchKernelGGL(k_node,     dim3(256), dim3(256), 0, stream, node, eidx, Wnm, bnm, out0);
}

// Round 2
// 33.920 us; speedup vs baseline: 1.1051x; 1.1051x over previous
//
#include <hip/hip_runtime.h>

// Problem constants (b=4, n=64, d=64, E=4096)
// z_t layout in ws: [b][d][i][k] -> ((b*64+d)*64+i)*64+k   (4 MB)
// a1[r][e], a3[r][e] : r = b*64+i (node row), 64 KB each

// K1: fused  pathlin (z = pe@Whz+b, transposed store)  +  nodeproj (a1,a3)
//            + node MLP (segment-sum + relu MLP + residual)
__global__ __launch_bounds__(256) void k_phase1(
    const float* __restrict__ ne, const float* __restrict__ pe,
    const int* __restrict__ eidx,
    const float* __restrict__ Whz, const float* __restrict__ bhz,
    const float* __restrict__ Wzz,
    const float* __restrict__ Wnm, const float* __restrict__ bnm,
    float* __restrict__ zt, float* __restrict__ a1, float* __restrict__ a3,
    float* __restrict__ out0) {
  int bi = blockIdx.x;            // b*64 + i  == node row r
  int b  = bi >> 6, i = bi & 63;
  int t = threadIdx.x, lane = t & 63, g = t >> 6;
  __shared__ float sA[64][64];    // pe tile; later aliased as elist (ints)
  __shared__ float sB[64][64];    // Whz
  __shared__ float sC[64][65];    // z[k][d], padded for transpose read
  __shared__ float part[4][64];
  __shared__ float nl[64], al[64];
  int* elist = (int*)&sA[0][0];   // 4096 ints = 16KB, valid after compute

  // ---- pathlin: stage pe row-block and Whz ----
  const float* peb = pe + (size_t)bi * 4096;
  for (int r = g; r < 64; r += 4) {
    sA[r][lane] = peb[r * 64 + lane];
    sB[r][lane] = Whz[r * 64 + lane];
  }
  __syncthreads();
  // lane = d, wave g owns k in [g*16, g*16+16)
  float acc[16];
  float bv = bhz[lane];
#pragma unroll
  for (int kk = 0; kk < 16; ++kk) acc[kk] = bv;
  int k0 = g * 16;
  for (int c = 0; c < 64; c += 4) {
    float w0 = sB[c + 0][lane], w1 = sB[c + 1][lane];
    float w2 = sB[c + 2][lane], w3 = sB[c + 3][lane];
#pragma unroll
    for (int kk = 0; kk < 16; ++kk) {
      const float4 p = *(const float4*)&sA[k0 + kk][c];   // wave-uniform b128
      acc[kk] += p.x * w0 + p.y * w1 + p.z * w2 + p.w * w3;
    }
  }
#pragma unroll
  for (int kk = 0; kk < 16; ++kk) sC[k0 + kk][lane] = acc[kk];
  __syncthreads();                 // sA/sB dead from here; sC holds z
  // write transposed: lane = k, wave g owns d in [g*16, g*16+16)
  float* ztb = zt + (size_t)b * 262144 + (size_t)i * 64;   // + d*4096 + k
#pragma unroll
  for (int dd = 0; dd < 16; ++dd) {
    int d2 = g * 16 + dd;
    ztb[(size_t)d2 * 4096 + lane] = sC[lane][d2];
  }

  // ---- node MLP for row r = bi (independent of path pipeline) ----
  const int* srcv = eidx;
  const int* dstv = eidx + 4096;
  // deterministic ballot compaction; wave g scans edges [g*1024,(g+1)*1024)
  int cntw = 0;
  unsigned long long ltmask = (lane == 63) ? 0x7fffffffffffffffull
                                           : ((1ull << lane) - 1ull);
  for (int q = 0; q < 16; ++q) {
    int e2 = g * 1024 + q * 64 + lane;
    bool match = (dstv[e2] == bi);
    unsigned long long mask = __ballot(match);
    if (match) {
      int pos = cntw + __popcll(mask & ltmask);
      elist[g * 1024 + pos] = srcv[e2];
    }
    cntw += __popcll(mask);
  }
  // wave g sums its own segment in fixed order (deterministic)
  float accA = 0.f;
  for (int m = 0; m < cntw; ++m) accA += ne[elist[g * 1024 + m] * 64 + lane];
  part[g][lane] = accA;
  if (g == 0) nl[lane] = ne[bi * 64 + lane];
  __syncthreads();
  if (g == 0)
    al[lane] = part[0][lane] + part[1][lane] + part[2][lane] + part[3][lane];
  __syncthreads();
  // u_node row: wave g handles d2 in [g*16, g*16+16)
  float s = 0.f;
  for (int d2 = g * 16; d2 < g * 16 + 16; ++d2) {
    s += nl[d2] * Wnm[d2 * 64 + lane] + al[d2] * Wnm[(64 + d2) * 64 + lane];
  }
  part[g][lane] = s;

  // ---- nodeproj for row bi (waves 2,3 idle; tiny) ----
  if (g == 0) {
    const float* nr = ne + bi * 64;
    float s1 = 0.f;
    for (int d2 = 0; d2 < 64; ++d2) s1 += nr[d2] * Wzz[d2 * 64 + lane];
    a1[bi * 64 + lane] = s1;
  } else if (g == 1) {
    const float* nr = ne + bi * 64;
    float s3 = 0.f;
    for (int d2 = 0; d2 < 64; ++d2) s3 += nr[d2] * Wzz[(128 + d2) * 64 + lane];
    a3[bi * 64 + lane] = s3;
  }
  __syncthreads();
  if (g == 0) {
    float v = part[0][lane] + part[1][lane] + part[2][lane] + part[3][lane]
              + bnm[lane];
    v = fmaxf(v, 0.f);
    out0[bi * 64 + lane] = v + nl[lane];
  }
}

// K2: tropical max-plus square per (b,d) slice, in place on zt
__global__ __launch_bounds__(256) void k_tropical(float* __restrict__ zt) {
  int blk = blockIdx.x;           // b*64 + d
  float* Ag = zt + (size_t)blk * 4096;
  __shared__ float A[64][64];
  int t = threadIdx.x, lane = t & 63, g = t >> 6;
  {
    const float4* s4 = (const float4*)Ag;
    float4* d4 = (float4*)&A[0][0];
    for (int idx = t; idx < 1024; idx += 256) d4[idx] = s4[idx];
  }
  __syncthreads();
  int j = lane, i0 = g * 16;
  float acc[16];
#pragma unroll
  for (int ii = 0; ii < 16; ++ii) acc[ii] = A[i0 + ii][j];  // max(z_conv, z)
  for (int k = 0; k < 64; k += 4) {
    float b0 = A[k + 0][j], b1 = A[k + 1][j];
    float b2 = A[k + 2][j], b3 = A[k + 3][j];
#pragma unroll
    for (int ii = 0; ii < 16; ++ii) {
      const float4 a = *(const float4*)&A[i0 + ii][k];      // wave-uniform b128
      float m0 = fmaxf(a.x + b0, a.y + b1);
      float m1 = fmaxf(a.z + b2, a.w + b3);
      acc[ii] = fmaxf(acc[ii], fmaxf(m0, m1));
    }
  }
#pragma unroll
  for (int ii = 0; ii < 16; ++ii) Ag[(i0 + ii) * 64 + j] = acc[ii];
}

// K3: u_path = relu(a1 + z@W2 + a3 + bzz) + pe  (residual), per (b,i) row-block
__global__ __launch_bounds__(256) void k_upath(
    const float* __restrict__ zt, const float* __restrict__ Wzz,
    const float* __restrict__ bzz, const float* __restrict__ a1,
    const float* __restrict__ a3, const float* __restrict__ pe,
    float* __restrict__ out1) {
  int bi = blockIdx.x;            // b*64 + i
  int b  = bi >> 6;
  int t = threadIdx.x, lane = t & 63, g = t >> 6;
  __shared__ float zf[64][64];    // [d][j]
  __shared__ float W2[64][64];    // [d][e] = W_zz rows 64..127
  const float* ztb = zt + (size_t)b * 262144 + (size_t)(bi & 63) * 64;
  for (int d2 = g; d2 < 64; d2 += 4) {
    zf[d2][lane] = ztb[(size_t)d2 * 4096 + lane];
    W2[d2][lane] = Wzz[(64 + d2) * 64 + lane];
  }
  __syncthreads();
  int e = lane, j0 = g * 16;
  float base = a1[bi * 64 + e] + bzz[e];
  float acc[16];
#pragma unroll
  for (int jj = 0; jj < 16; ++jj) acc[jj] = base;
  for (int d2 = 0; d2 < 64; ++d2) {
    float w = W2[d2][e];
#pragma unroll
    for (int jj = 0; jj < 16; jj += 4) {
      const float4 z4 = *(const float4*)&zf[d2][j0 + jj];   // wave-uniform b128
      acc[jj + 0] += z4.x * w;
      acc[jj + 1] += z4.y * w;
      acc[jj + 2] += z4.z * w;
      acc[jj + 3] += z4.w * w;
    }
  }
  const float* a3b = a3 + (size_t)(b * 64) * 64;
  size_t obase = (size_t)bi * 4096;
#pragma unroll
  for (int jj = 0; jj < 16; ++jj) {
    int j = j0 + jj;
    float v = acc[jj] + a3b[j * 64 + e];
    v = fmaxf(v, 0.f);
    out1[obase + j * 64 + e] = v + pe[obase + j * 64 + e];
  }
}

extern "C" void kernel_launch(void* const* d_in, const int* in_sizes, int n_in,
                              void* d_out, int out_size, void* d_ws, size_t ws_size,
                              hipStream_t stream) {
  const float* node = (const float*)d_in[0];
  const float* pe   = (const float*)d_in[1];
  const int*   eidx = (const int*)d_in[2];
  const float* Whz  = (const float*)d_in[3];
  const float* bhz  = (const float*)d_in[4];
  const float* Wzz  = (const float*)d_in[5];
  const float* bzz  = (const float*)d_in[6];
  const float* Wnm  = (const float*)d_in[7];
  const float* bnm  = (const float*)d_in[8];
  float* out0 = (float*)d_out;
  float* out1 = out0 + 16384;
  float* zt = (float*)d_ws;                 // 4 MB
  float* a1 = zt + 4 * 64 * 64 * 64;        // 64 KB
  float* a3 = a1 + 256 * 64;                // 64 KB

  hipLaunchKernelGGL(k_phase1, dim3(256), dim3(256), 0, stream,
                     node, pe, eidx, Whz, bhz, Wzz, Wnm, bnm, zt, a1, a3, out0);
  hipLaunchKernelGGL(k_tropical, dim3(256), dim3(256), 0, stream, zt);
  hipLaunchKernelGGL(k_upath, dim3(256), dim3(256), 0, stream,
                     zt, Wzz, bzz, a1, a3, pe, out1);
}

// Round 3
// 31.453 us; speedup vs baseline: 1.1917x; 1.0785x over previous
//
#include <hip/hip_runtime.h>

// Problem constants (b=4, n=64, d=64, E=4096)
// zt  layout: [b][d][i][k] -> ((b*64+d)*64+i)*64+k   (4 MB)
// zt2: tropical output, same layout (4 MB)
// a1[r][e], a3[r][e] : r = b*64+i (node row), 64 KB each

// K1: z = pe@Whz + b, stored transposed. grid = 1024: (bi, quarter-of-k)
__global__ __launch_bounds__(256) void k_pathlin(
    const float* __restrict__ pe, const float* __restrict__ Whz,
    const float* __restrict__ bhz, float* __restrict__ zt) {
  int blk = blockIdx.x;
  int bi = blk >> 2, q = blk & 3;         // bi = b*64+i, q = k-quarter
  int b = bi >> 6, i = bi & 63;
  int t = threadIdx.x, lane = t & 63, g = t >> 6;
  __shared__ float sA[16][64];            // pe rows k in [q*16, q*16+16)
  __shared__ float sB[64][64];            // Whz
  ((float4*)sA)[t] = ((const float4*)(pe + (size_t)bi * 4096 + q * 1024))[t];
  {
    const float4* W4 = (const float4*)Whz;
    float4* sB4 = (float4*)sB;
#pragma unroll
    for (int it = 0; it < 4; ++it) sB4[t + 256 * it] = W4[t + 256 * it];
  }
  __syncthreads();
  // lane = d; wave g owns k_local in [g*4, g*4+4)
  float bv = bhz[lane];
  float acc[4] = {bv, bv, bv, bv};
  int kl0 = g * 4;
  for (int c = 0; c < 64; c += 4) {
    float w0 = sB[c + 0][lane], w1 = sB[c + 1][lane];
    float w2 = sB[c + 2][lane], w3 = sB[c + 3][lane];
#pragma unroll
    for (int kk = 0; kk < 4; ++kk) {
      const float4 p = *(const float4*)&sA[kl0 + kk][c];   // wave-uniform b128
      acc[kk] += p.x * w0 + p.y * w1 + p.z * w2 + p.w * w3;
    }
  }
  // direct transposed store: 4 consecutive k per thread -> one float4
  float* dst = zt + (size_t)b * 262144 + (size_t)lane * 4096
             + (size_t)i * 64 + q * 16 + kl0;
  *(float4*)dst = make_float4(acc[0], acc[1], acc[2], acc[3]);
}

// K2: blocks [0,1024): tropical quarter-slices; blocks [1024,1280): node MLP + nodeproj
__global__ __launch_bounds__(256) void k_trop_node(
    const float* __restrict__ zt, float* __restrict__ zt2,
    const float* __restrict__ ne, const int* __restrict__ eidx,
    const float* __restrict__ Wzz, const float* __restrict__ Wnm,
    const float* __restrict__ bnm,
    float* __restrict__ a1, float* __restrict__ a3, float* __restrict__ out0) {
  int t = threadIdx.x, lane = t & 63, g = t >> 6;
  __shared__ float A[64][64];
  __shared__ float part[4][64];
  __shared__ float nlal[2][64];
  if (blockIdx.x < 1024) {
    int slice = blockIdx.x >> 2, iq = blockIdx.x & 3;   // slice = b*64+d
    const float4* s4 = (const float4*)(zt + (size_t)slice * 4096);
    float4* d4 = (float4*)&A[0][0];
#pragma unroll
    for (int it = 0; it < 4; ++it) d4[t + 256 * it] = s4[t + 256 * it];
    __syncthreads();
    int j = lane, i0 = iq * 16 + g * 4;
    float acc[4];
#pragma unroll
    for (int ii = 0; ii < 4; ++ii) acc[ii] = A[i0 + ii][j];  // max(z_conv, z)
    for (int k = 0; k < 64; k += 4) {
      float b0 = A[k + 0][j], b1 = A[k + 1][j];
      float b2 = A[k + 2][j], b3 = A[k + 3][j];
#pragma unroll
      for (int ii = 0; ii < 4; ++ii) {
        const float4 a = *(const float4*)&A[i0 + ii][k];     // wave-uniform b128
        float m0 = fmaxf(a.x + b0, a.y + b1);
        float m1 = fmaxf(a.z + b2, a.w + b3);
        acc[ii] = fmaxf(acc[ii], fmaxf(m0, m1));
      }
    }
    float* Og = zt2 + (size_t)slice * 4096;
#pragma unroll
    for (int ii = 0; ii < 4; ++ii) Og[(i0 + ii) * 64 + j] = acc[ii];
  } else {
    int r = blockIdx.x - 1024;
    int* elist = (int*)&A[0][0];          // 4096 ints, wave-segmented
    const int* srcv = eidx;
    const int* dstv = eidx + 4096;
    int cntw = 0;
    unsigned long long ltmask = (lane == 63) ? 0x7fffffffffffffffull
                                             : ((1ull << lane) - 1ull);
    for (int q = 0; q < 16; ++q) {
      int e2 = g * 1024 + q * 64 + lane;
      bool match = (dstv[e2] == r);
      unsigned long long mask = __ballot(match);
      if (match) {
        int pos = cntw + __popcll(mask & ltmask);
        elist[g * 1024 + pos] = srcv[e2];
      }
      cntw += __popcll(mask);
    }
    float accA = 0.f;
    for (int m = 0; m < cntw; ++m) accA += ne[elist[g * 1024 + m] * 64 + lane];
    part[g][lane] = accA;
    if (g == 0) nlal[0][lane] = ne[r * 64 + lane];
    __syncthreads();
    if (g == 0)
      nlal[1][lane] = part[0][lane] + part[1][lane] + part[2][lane] + part[3][lane];
    __syncthreads();
    // u_node partials: wave g handles d2 in [g*16, g*16+16)
    float s = 0.f;
    for (int d2 = g * 16; d2 < g * 16 + 16; ++d2) {
      s += nlal[0][d2] * Wnm[d2 * 64 + lane]
         + nlal[1][d2] * Wnm[(64 + d2) * 64 + lane];
    }
    part[g][lane] = s;
    // nodeproj for row r (waves 2,3 idle; tiny)
    if (g == 0) {
      const float* nr = ne + r * 64;
      float s1 = 0.f;
      for (int d2 = 0; d2 < 64; ++d2) s1 += nr[d2] * Wzz[d2 * 64 + lane];
      a1[r * 64 + lane] = s1;
    } else if (g == 1) {
      const float* nr = ne + r * 64;
      float s3 = 0.f;
      for (int d2 = 0; d2 < 64; ++d2) s3 += nr[d2] * Wzz[(128 + d2) * 64 + lane];
      a3[r * 64 + lane] = s3;
    }
    __syncthreads();
    if (g == 0) {
      float v = part[0][lane] + part[1][lane] + part[2][lane] + part[3][lane]
                + bnm[lane];
      v = fmaxf(v, 0.f);
      out0[r * 64 + lane] = v + nlal[0][lane];
    }
  }
}

// K3: u_path row-block. grid = 1024: (bi, quarter-of-j)
__global__ __launch_bounds__(256) void k_upath(
    const float* __restrict__ zt2, const float* __restrict__ Wzz,
    const float* __restrict__ bzz, const float* __restrict__ a1,
    const float* __restrict__ a3, const float* __restrict__ pe,
    float* __restrict__ out1) {
  int blk = blockIdx.x;
  int bi = blk >> 2, jq = blk & 3;
  int b = bi >> 6, i = bi & 63;
  int t = threadIdx.x, lane = t & 63, g = t >> 6;
  __shared__ float W2[64][64];            // W_zz rows 64..127: [d][e]
  __shared__ float sZ[64][16];            // zf[d][j_local]
  {
    const float4* W4 = (const float4*)(Wzz + 4096);
    float4* W24 = (float4*)W2;
#pragma unroll
    for (int it = 0; it < 4; ++it) W24[t + 256 * it] = W4[t + 256 * it];
  }
  {
    int d2 = t >> 2, c4 = t & 3;
    const float* src = zt2 + (size_t)b * 262144 + (size_t)d2 * 4096
                     + (size_t)i * 64 + jq * 16 + c4 * 4;
    *(float4*)&sZ[d2][c4 * 4] = *(const float4*)src;
  }
  __syncthreads();
  int e = lane;
  float base = a1[bi * 64 + e] + bzz[e];
  float acc[4] = {base, base, base, base};
  for (int d2 = 0; d2 < 64; ++d2) {
    float w = W2[d2][e];
    const float4 z4 = *(const float4*)&sZ[d2][g * 4];      // wave-uniform b128
    acc[0] += z4.x * w;
    acc[1] += z4.y * w;
    acc[2] += z4.z * w;
    acc[3] += z4.w * w;
  }
  const float* a3b = a3 + (size_t)(b * 64) * 64;
  size_t obase = (size_t)bi * 4096;
#pragma unroll
  for (int jj = 0; jj < 4; ++jj) {
    int j = jq * 16 + g * 4 + jj;
    float v = acc[jj] + a3b[j * 64 + e];
    v = fmaxf(v, 0.f);
    out1[obase + j * 64 + e] = v + pe[obase + j * 64 + e];
  }
}

extern "C" void kernel_launch(void* const* d_in, const int* in_sizes, int n_in,
                              void* d_out, int out_size, void* d_ws, size_t ws_size,
                              hipStream_t stream) {
  const float* node = (const float*)d_in[0];
  const float* pe   = (const float*)d_in[1];
  const int*   eidx = (const int*)d_in[2];
  const float* Whz  = (const float*)d_in[3];
  const float* bhz  = (const float*)d_in[4];
  const float* Wzz  = (const float*)d_in[5];
  const float* bzz  = (const float*)d_in[6];
  const float* Wnm  = (const float*)d_in[7];
  const float* bnm  = (const float*)d_in[8];
  float* out0 = (float*)d_out;
  float* out1 = out0 + 16384;
  float* zt  = (float*)d_ws;                // 4 MB
  float* a1  = zt + 1048576;                // 64 KB
  float* a3  = a1 + 16384;                  // 64 KB
  float* zt2 = a3 + 16384;                  // 4 MB

  hipLaunchKernelGGL(k_pathlin, dim3(1024), dim3(256), 0, stream, pe, Whz, bhz, zt);
  hipLaunchKernelGGL(k_trop_node, dim3(1280), dim3(256), 0, stream,
                     zt, zt2, node, eidx, Wzz, Wnm, bnm, a1, a3, out0);
  hipLaunchKernelGGL(k_upath, dim3(1024), dim3(256), 0, stream,
                     zt2, Wzz, bzz, a1, a3, pe, out1);
}